// Round 2
// baseline (178.606 us; speedup 1.0000x reference)
//
#include <hip/hip_runtime.h>

// Problem constants
constexpr int N  = 50000;    // nodes
constexpr int E  = 1600000;  // edges
constexpr int CH = 128;      // channels

// Bucket slab parameters
constexpr int BSZ  = 64;                   // nodes per bucket
constexpr int NB   = (N + BSZ - 1) / BSZ;  // 782 buckets (10 bits)
constexpr int CAP  = 2560;                 // slab capacity (mean 2046, +11 sigma)
constexpr int SRTCAP = CAP + BSZ * 31 + 64; // 4608: padded CSR worst case
constexpr int PBLK = 256;                  // scatter partition blocks
constexpr int EPB  = E / PBLK;             // 6250 edges per partition block (exact)
constexpr int GEMM_BLOCKS = N / 16;        // 3125

// Workspace layout (bytes, 256-aligned)
constexpr size_t H_OFF     = 0;                        // h bf16 [(N+1)*CH], row N = zeros
constexpr size_t H_SZ      = (size_t)(N + 1) * CH * 2; // 12,800,256 (256-aligned)
constexpr size_t PAIRS_OFF = H_OFF + H_SZ;             // slabs [NB][CAP] u32 packed
constexpr size_t PAIRS_SZ  = (size_t)NB * CAP * 4;     // 8,007,680
constexpr size_t GCUR_OFF  = PAIRS_OFF + PAIRS_SZ;     // bump cursors [NB] i32
constexpr size_t GCUR_SZ   = 3328;
constexpr size_t REQUIRED  = GCUR_OFF + GCUR_SZ;       // ~20.8 MB
constexpr size_t FB_REQUIRED = H_SZ;                   // fallback: h only

// float -> bf16 round-to-nearest-even (finite inputs)
static __device__ __forceinline__ ushort f2bf(float f) {
    unsigned u = __float_as_uint(f);
    return (ushort)((u + 0x7fffu + ((u >> 16) & 1u)) >> 16);
}
static __device__ __forceinline__ float bf_lo(unsigned u) { return __uint_as_float(u << 16); }
static __device__ __forceinline__ float bf_hi(unsigned u) { return __uint_as_float(u & 0xffff0000u); }

typedef __attribute__((ext_vector_type(8))) short bf16x8;
typedef __attribute__((ext_vector_type(4))) float f32x4;

// ---------------- GEMM body: 16 rows x 128 cols per 256-thread block ----------------
// mfma_f32_16x16x32_bf16, verified layouts (m89/m91): A[m=lane&15][k=q*8+j],
// B[n=lane&15][k=q*8+j], D col=lane&15,row=q*4+reg. W converted in-register.
static __device__ __forceinline__ void gemm_body(int gb, int tid,
                                                 const float* __restrict__ x,
                                                 const float* __restrict__ W,
                                                 const float* __restrict__ bias,
                                                 ushort* __restrict__ h) {
    const int m    = tid & 15;
    const int q    = (tid >> 4) & 3;
    const int wave = tid >> 6;
    const int r0   = gb * 16;
    const int c0   = wave * 32;

    const float* xrow = x + (size_t)(r0 + m) * CH + q * 8;
    const float* wr0  = W + (size_t)(c0 + m) * CH + q * 8;
    const float* wr1  = wr0 + 16 * CH;

    f32x4 acc0 = {0.f, 0.f, 0.f, 0.f};
    f32x4 acc1 = {0.f, 0.f, 0.f, 0.f};

#pragma unroll
    for (int kc = 0; kc < CH; kc += 32) {
        float4 xa = *(const float4*)(xrow + kc);
        float4 xb = *(const float4*)(xrow + kc + 4);
        float4 wa0 = *(const float4*)(wr0 + kc);
        float4 wb0 = *(const float4*)(wr0 + kc + 4);
        float4 wa1 = *(const float4*)(wr1 + kc);
        float4 wb1 = *(const float4*)(wr1 + kc + 4);
        bf16x8 a, b0, b1;
        a[0] = (short)f2bf(xa.x); a[1] = (short)f2bf(xa.y);
        a[2] = (short)f2bf(xa.z); a[3] = (short)f2bf(xa.w);
        a[4] = (short)f2bf(xb.x); a[5] = (short)f2bf(xb.y);
        a[6] = (short)f2bf(xb.z); a[7] = (short)f2bf(xb.w);
        b0[0] = (short)f2bf(wa0.x); b0[1] = (short)f2bf(wa0.y);
        b0[2] = (short)f2bf(wa0.z); b0[3] = (short)f2bf(wa0.w);
        b0[4] = (short)f2bf(wb0.x); b0[5] = (short)f2bf(wb0.y);
        b0[6] = (short)f2bf(wb0.z); b0[7] = (short)f2bf(wb0.w);
        b1[0] = (short)f2bf(wa1.x); b1[1] = (short)f2bf(wa1.y);
        b1[2] = (short)f2bf(wa1.z); b1[3] = (short)f2bf(wa1.w);
        b1[4] = (short)f2bf(wb1.x); b1[5] = (short)f2bf(wb1.y);
        b1[6] = (short)f2bf(wb1.z); b1[7] = (short)f2bf(wb1.w);
        acc0 = __builtin_amdgcn_mfma_f32_16x16x32_bf16(a, b0, acc0, 0, 0, 0);
        acc1 = __builtin_amdgcn_mfma_f32_16x16x32_bf16(a, b1, acc1, 0, 0, 0);
    }

    const int col0 = c0 + m;
    const float bb0 = bias[col0];
    const float bb1 = bias[col0 + 16];
#pragma unroll
    for (int r = 0; r < 4; r++) {
        size_t row = (size_t)(r0 + q * 4 + r) * CH;
        h[row + col0]      = f2bf(acc0[r] + bb0);
        h[row + col0 + 16] = f2bf(acc1[r] + bb1);
    }
}

// ---------------- fused: sorted edge scatter (blocks 0..PBLK) | GEMM (rest) ----------------
// Scatter role (R11): full in-LDS counting sort so global slab writes are
// SEQUENTIAL per (bucket,block) run. Flow: stage packed (bkt<<22|dstLoc<<16|src)
// to LDS with fused int hist -> ONE global atomicAdd per bucket (bump reserve)
// -> per-wave shfl scan (782 buckets, 4/thread) -> LDS sort of 16-bit local
// indices -> sequential copy-out to pairs[gpos[bkt] + (i - lstart[bkt])].
// gcur must be pre-zeroed. Block 0 additionally zeros h row N (pad target).
__global__ __launch_bounds__(256) void gemm_and_scatter(const float* __restrict__ x,
                                                        const float* __restrict__ W,
                                                        const float* __restrict__ bias,
                                                        ushort* __restrict__ h,
                                                        const int* __restrict__ ei,
                                                        int* __restrict__ gcur,
                                                        unsigned* __restrict__ pairs) {
    __shared__ unsigned raw[EPB];      // 25000 B packed edges
    __shared__ ushort   srt16[EPB];    // 12500 B sorted local indices
    __shared__ int cnt[NB];            //  3128 B
    __shared__ int lstart[NB];         //  3128 B
    __shared__ int gpos[NB];           //  3128 B
    __shared__ int cur[NB];            //  3128 B
    __shared__ int wsum[4];
    const int bid = blockIdx.x;
    const int tid = threadIdx.x;

    if (bid >= PBLK) {
        gemm_body(bid - PBLK, tid, x, W, bias, h);
        return;
    }

    const int k = bid;
    const int* dp = ei + k * EPB;
    const int* sp = ei + E + k * EPB;

    // block 0: zero the pad row h[N] (256 B) for agg's sentinel loads
    if (bid == 0 && tid < 64) ((unsigned*)(h + (size_t)N * CH))[tid] = 0u;

    // zero hist, then stage with fused histogram
    for (int j = tid; j < NB; j += 256) cnt[j] = 0;
    __syncthreads();
    for (int i = tid; i < EPB; i += 256) {
        int d = dp[i], s = sp[i];
        unsigned w = ((unsigned)(d >> 6) << 22) | ((unsigned)(d & (BSZ - 1)) << 16) | (unsigned)s;
        raw[i] = w;
        atomicAdd(&cnt[w >> 22], 1);
    }
    __syncthreads();

    // global bump-reserve: one atomic per non-empty bucket
    for (int j = tid; j < NB; j += 256) {
        int c = cnt[j];
        gpos[j] = j * CAP + (c ? atomicAdd(&gcur[j], c) : 0);
    }

    // exclusive scan of cnt[0..NB): thread t owns buckets [t*4, t*4+4),
    // per-wave shfl inclusive scan + 4-entry wave-sum combine (2 barriers total)
    {
        const int base = tid * 4;
        int s = 0;
#pragma unroll
        for (int i = 0; i < 4; i++) { int j = base + i; if (j < NB) s += cnt[j]; }
        const int lane = tid & 63;
        const int wid  = tid >> 6;
        int incl = s;
#pragma unroll
        for (int o = 1; o < 64; o <<= 1) {
            int u = __shfl_up(incl, o);
            if (lane >= o) incl += u;
        }
        if (lane == 63) wsum[wid] = incl;
        __syncthreads();
        int run = incl - s;
        for (int w = 0; w < wid; w++) run += wsum[w];
#pragma unroll
        for (int i = 0; i < 4; i++) {
            int j = base + i;
            if (j < NB) { lstart[j] = run; cur[j] = run; run += cnt[j]; }
        }
    }
    __syncthreads();

    // LDS sort: place each edge's local index at its sorted position
    for (int i = tid; i < EPB; i += 256) {
        int p = atomicAdd(&cur[raw[i] >> 22], 1);
        srt16[p] = (ushort)i;
    }
    __syncthreads();

    // sequential copy-out: consecutive i -> consecutive slab addresses per run
    for (int i = tid; i < EPB; i += 256) {
        unsigned w = raw[srt16[i]];
        int bkt = w >> 22;
        int gdst = gpos[bkt] + (i - lstart[bkt]);
        if (gdst < (bkt + 1) * CAP)          // defensive: never cross slab end
            pairs[gdst] = w;
    }
}

// ---------------- fused local-CSR build + pull aggregation (1 bucket / block) ----------------
// 8 waves. Stage the bucket slab to LDS with fused hist, wave0 shfl-scan of
// PADDED counts (each node's segment rounded up to 32; pad slots hold sentinel
// src=N -> zero row, L1-resident), LDS sort -> CSR. Aggregation: wave owns 8
// nodes; QUARTER-wave (16 lanes) per edge, lane reads uint4 = 8 bf16 channels.
// Branch-free inner loop: explicit sidx[8]/v[8] array phases (static unroll)
// + __launch_bounds__(512,2) so the allocator keeps 8 uint4 loads in flight
// (R1 post-mortem: VGPR_Count=32 proved the compiler serialized to ~2 deep).
// Reduce across quarters via shfl_xor(16|32).
__global__ __launch_bounds__(512, 2) void agg_fused(const ushort* __restrict__ h,
                                                    const unsigned* __restrict__ pairs,
                                                    const int* __restrict__ gcur,
                                                    float* __restrict__ out) {
    __shared__ unsigned raw[CAP];        // 10240 B
    __shared__ ushort   srt[SRTCAP];     //  9216 B
    __shared__ int hist[BSZ], offs[BSZ], cur[BSZ], cpad[BSZ];
    const int b = blockIdx.x, t = threadIdx.x;
    const int cnt = min(gcur[b], CAP);
    const int wave = t >> 6;
    const int lane = t & 63;
    const int quarter = lane >> 4;       // 0..3: which edge of a 4-edge group
    const int cq      = lane & 15;       // channel octet 0..15 (8 ch each)

    if (t < BSZ) hist[t] = 0;
    __syncthreads();

    const unsigned* slab = pairs + (size_t)b * CAP;
    for (int i = t; i < cnt; i += 512) {
        unsigned w = slab[i];
        raw[i] = w;
        atomicAdd(&hist[(w >> 16) & (BSZ - 1)], 1);
    }
    __syncthreads();

    // wave0: pad counts to multiple of 32, shfl inclusive scan (no ladder)
    if (t < BSZ) {
        int c  = hist[t];
        int cp = (c + 31) & ~31;
        int incl = cp;
#pragma unroll
        for (int o = 1; o < 64; o <<= 1) {
            int u = __shfl_up(incl, o);
            if (lane >= o) incl += u;
        }
        offs[t] = incl - cp;
        cur[t]  = incl - cp;
        cpad[t] = cp;
    }
    __syncthreads();

    // sentinel-fill the padded CSR, then sort actual edges into place
    const int tot = offs[BSZ - 1] + cpad[BSZ - 1];
    for (int i = t; i < tot; i += 512) srt[i] = (ushort)N;
    __syncthreads();
    for (int i = t; i < cnt; i += 512) {
        unsigned w = raw[i];
        int p = atomicAdd(&cur[(w >> 16) & (BSZ - 1)], 1);
        srt[p] = (ushort)(w & 0xffffu);
    }
    __syncthreads();

    const ushort* hp = h + (size_t)cq * 8;   // this lane's 8 channels

#pragma unroll 1
    for (int j = 0; j < 8; j++) {
        const int nl = wave * 8 + j;
        const int st = offs[nl];
        const int cp = cpad[nl];
        float a0 = 0.f, a1 = 0.f, a2 = 0.f, a3 = 0.f;
        float a4 = 0.f, a5 = 0.f, a6 = 0.f, a7 = 0.f;
        for (int i = 0; i < cp; i += 32) {
            const int e0 = st + i + quarter;
            int sidx[8];
#pragma unroll
            for (int u = 0; u < 8; u++) sidx[u] = srt[e0 + 4 * u];
            uint4 v[8];
#pragma unroll
            for (int u = 0; u < 8; u++) v[u] = *(const uint4*)(hp + (size_t)sidx[u] * CH);
#pragma unroll
            for (int u = 0; u < 8; u++) {
                a0 += bf_lo(v[u].x); a1 += bf_hi(v[u].x);
                a2 += bf_lo(v[u].y); a3 += bf_hi(v[u].y);
                a4 += bf_lo(v[u].z); a5 += bf_hi(v[u].z);
                a6 += bf_lo(v[u].w); a7 += bf_hi(v[u].w);
            }
        }
        a0 += __shfl_xor(a0, 16); a0 += __shfl_xor(a0, 32);
        a1 += __shfl_xor(a1, 16); a1 += __shfl_xor(a1, 32);
        a2 += __shfl_xor(a2, 16); a2 += __shfl_xor(a2, 32);
        a3 += __shfl_xor(a3, 16); a3 += __shfl_xor(a3, 32);
        a4 += __shfl_xor(a4, 16); a4 += __shfl_xor(a4, 32);
        a5 += __shfl_xor(a5, 16); a5 += __shfl_xor(a5, 32);
        a6 += __shfl_xor(a6, 16); a6 += __shfl_xor(a6, 32);
        a7 += __shfl_xor(a7, 16); a7 += __shfl_xor(a7, 32);
        const int n = b * BSZ + nl;
        if (quarter == 0 && n < N) {
            float* op = out + (size_t)n * CH + cq * 8;
            *(float4*)(op)     = make_float4(a0, a1, a2, a3);
            *(float4*)(op + 4) = make_float4(a4, a5, a6, a7);
        }
    }
}

// ---------------- fallback path ----------------
__global__ __launch_bounds__(256) void gemm_only(const float* __restrict__ x,
                                                 const float* __restrict__ W,
                                                 const float* __restrict__ bias,
                                                 ushort* __restrict__ h) {
    gemm_body(blockIdx.x, threadIdx.x, x, W, bias, h);
}

__global__ void atomic_agg(const ushort* __restrict__ h, const int* __restrict__ ei,
                           float* __restrict__ out) {
    int tid = blockIdx.x * blockDim.x + threadIdx.x;
    int e  = tid >> 5;
    int cg = (tid & 31) * 4;
    if (e < E) {
        int d = ei[e];
        int s = ei[E + e];
        ushort4 v = *(const ushort4*)(h + (size_t)s * CH + cg);
        float* o = out + (size_t)d * CH + cg;
        atomicAdd(o + 0, __uint_as_float((unsigned)v.x << 16));
        atomicAdd(o + 1, __uint_as_float((unsigned)v.y << 16));
        atomicAdd(o + 2, __uint_as_float((unsigned)v.z << 16));
        atomicAdd(o + 3, __uint_as_float((unsigned)v.w << 16));
    }
}

extern "C" void kernel_launch(void* const* d_in, const int* in_sizes, int n_in,
                              void* d_out, int out_size, void* d_ws, size_t ws_size,
                              hipStream_t stream) {
    const float* x  = (const float*)d_in[0];
    const int*   ei = (const int*)d_in[1];   // [2][E] int32: row0=dst, row1=src
    const float* W  = (const float*)d_in[2];
    const float* b  = (const float*)d_in[3];
    float* out = (float*)d_out;

    char* ws = (char*)d_ws;
    ushort* h = (ushort*)(ws + H_OFF);

    if (ws_size >= REQUIRED) {
        unsigned* pairs = (unsigned*)(ws + PAIRS_OFF);
        int*      gcur  = (int*)(ws + GCUR_OFF);

        hipMemsetAsync(gcur, 0, NB * sizeof(int), stream);   // ws re-poisoned each call
        gemm_and_scatter<<<PBLK + GEMM_BLOCKS, 256, 0, stream>>>(x, W, b, h, ei, gcur, pairs);
        agg_fused<<<NB, 512, 0, stream>>>(h, pairs, gcur, out);
    } else if (ws_size >= FB_REQUIRED) {
        gemm_only<<<GEMM_BLOCKS, 256, 0, stream>>>(x, W, b, h);
        hipMemsetAsync(out, 0, (size_t)out_size * sizeof(float), stream);
        int total = E * 32;
        atomic_agg<<<(total + 255) / 256, 256, 0, stream>>>(h, ei, out);
    }
}

// Round 3
// 175.525 us; speedup vs baseline: 1.0175x; 1.0175x over previous
//
#include <hip/hip_runtime.h>

// Problem constants
constexpr int N  = 50000;    // nodes
constexpr int E  = 1600000;  // edges
constexpr int CH = 128;      // channels

// Bucket slab parameters
constexpr int BSZ  = 64;                   // nodes per bucket
constexpr int NB   = (N + BSZ - 1) / BSZ;  // 782 buckets (10 bits)
constexpr int CAP  = 2560;                 // slab capacity (mean 2046, +11 sigma)
constexpr int SRTCAP = CAP + BSZ * 31 + 64; // 4608: padded CSR worst case
constexpr int PBLK = 256;                  // scatter partition blocks
constexpr int EPB  = E / PBLK;             // 6250 edges per partition block (exact)
constexpr int GEMM_BLOCKS = N / 16;        // 3125

// Workspace layout (bytes, 256-aligned)
constexpr size_t H_OFF     = 0;                        // h bf16 [(N+1)*CH], row N = zeros
constexpr size_t H_SZ      = (size_t)(N + 1) * CH * 2; // 12,800,256 (256-aligned)
constexpr size_t PAIRS_OFF = H_OFF + H_SZ;             // slabs [NB][CAP] u32 packed
constexpr size_t PAIRS_SZ  = (size_t)NB * CAP * 4;     // 8,007,680
constexpr size_t GCUR_OFF  = PAIRS_OFF + PAIRS_SZ;     // bump cursors [NB] i32
constexpr size_t GCUR_SZ   = 3328;
constexpr size_t REQUIRED  = GCUR_OFF + GCUR_SZ;       // ~20.8 MB
constexpr size_t FB_REQUIRED = H_SZ;                   // fallback: h only

// float -> bf16 round-to-nearest-even (finite inputs)
static __device__ __forceinline__ ushort f2bf(float f) {
    unsigned u = __float_as_uint(f);
    return (ushort)((u + 0x7fffu + ((u >> 16) & 1u)) >> 16);
}
static __device__ __forceinline__ float bf_lo(unsigned u) { return __uint_as_float(u << 16); }
static __device__ __forceinline__ float bf_hi(unsigned u) { return __uint_as_float(u & 0xffff0000u); }

typedef __attribute__((ext_vector_type(8))) short bf16x8;
typedef __attribute__((ext_vector_type(4))) float f32x4;

// ---------------- GEMM body: 16 rows x 128 cols per 256-thread block ----------------
// mfma_f32_16x16x32_bf16, verified layouts (m89/m91): A[m=lane&15][k=q*8+j],
// B[n=lane&15][k=q*8+j], D col=lane&15,row=q*4+reg. W converted in-register.
static __device__ __forceinline__ void gemm_body(int gb, int tid,
                                                 const float* __restrict__ x,
                                                 const float* __restrict__ W,
                                                 const float* __restrict__ bias,
                                                 ushort* __restrict__ h) {
    const int m    = tid & 15;
    const int q    = (tid >> 4) & 3;
    const int wave = tid >> 6;
    const int r0   = gb * 16;
    const int c0   = wave * 32;

    const float* xrow = x + (size_t)(r0 + m) * CH + q * 8;
    const float* wr0  = W + (size_t)(c0 + m) * CH + q * 8;
    const float* wr1  = wr0 + 16 * CH;

    f32x4 acc0 = {0.f, 0.f, 0.f, 0.f};
    f32x4 acc1 = {0.f, 0.f, 0.f, 0.f};

#pragma unroll
    for (int kc = 0; kc < CH; kc += 32) {
        float4 xa = *(const float4*)(xrow + kc);
        float4 xb = *(const float4*)(xrow + kc + 4);
        float4 wa0 = *(const float4*)(wr0 + kc);
        float4 wb0 = *(const float4*)(wr0 + kc + 4);
        float4 wa1 = *(const float4*)(wr1 + kc);
        float4 wb1 = *(const float4*)(wr1 + kc + 4);
        bf16x8 a, b0, b1;
        a[0] = (short)f2bf(xa.x); a[1] = (short)f2bf(xa.y);
        a[2] = (short)f2bf(xa.z); a[3] = (short)f2bf(xa.w);
        a[4] = (short)f2bf(xb.x); a[5] = (short)f2bf(xb.y);
        a[6] = (short)f2bf(xb.z); a[7] = (short)f2bf(xb.w);
        b0[0] = (short)f2bf(wa0.x); b0[1] = (short)f2bf(wa0.y);
        b0[2] = (short)f2bf(wa0.z); b0[3] = (short)f2bf(wa0.w);
        b0[4] = (short)f2bf(wb0.x); b0[5] = (short)f2bf(wb0.y);
        b0[6] = (short)f2bf(wb0.z); b0[7] = (short)f2bf(wb0.w);
        b1[0] = (short)f2bf(wa1.x); b1[1] = (short)f2bf(wa1.y);
        b1[2] = (short)f2bf(wa1.z); b1[3] = (short)f2bf(wa1.w);
        b1[4] = (short)f2bf(wb1.x); b1[5] = (short)f2bf(wb1.y);
        b1[6] = (short)f2bf(wb1.z); b1[7] = (short)f2bf(wb1.w);
        acc0 = __builtin_amdgcn_mfma_f32_16x16x32_bf16(a, b0, acc0, 0, 0, 0);
        acc1 = __builtin_amdgcn_mfma_f32_16x16x32_bf16(a, b1, acc1, 0, 0, 0);
    }

    const int col0 = c0 + m;
    const float bb0 = bias[col0];
    const float bb1 = bias[col0 + 16];
#pragma unroll
    for (int r = 0; r < 4; r++) {
        size_t row = (size_t)(r0 + q * 4 + r) * CH;
        h[row + col0]      = f2bf(acc0[r] + bb0);
        h[row + col0 + 16] = f2bf(acc1[r] + bb1);
    }
}

// ---------------- fused: sorted edge scatter (blocks 0..PBLK) | GEMM (rest) ----------------
// Scatter role (R11): full in-LDS counting sort so global slab writes are
// SEQUENTIAL per (bucket,block) run. Flow: stage packed (bkt<<22|dstLoc<<16|src)
// to LDS with fused int hist -> ONE global atomicAdd per bucket (bump reserve)
// -> per-wave shfl scan (782 buckets, 4/thread) -> LDS sort of 16-bit local
// indices -> sequential copy-out to pairs[gpos[bkt] + (i - lstart[bkt])].
// gcur must be pre-zeroed. Block 0 additionally zeros h row N (pad target).
__global__ __launch_bounds__(256) void gemm_and_scatter(const float* __restrict__ x,
                                                        const float* __restrict__ W,
                                                        const float* __restrict__ bias,
                                                        ushort* __restrict__ h,
                                                        const int* __restrict__ ei,
                                                        int* __restrict__ gcur,
                                                        unsigned* __restrict__ pairs) {
    __shared__ unsigned raw[EPB];      // 25000 B packed edges
    __shared__ ushort   srt16[EPB];    // 12500 B sorted local indices
    __shared__ int cnt[NB];            //  3128 B
    __shared__ int lstart[NB];         //  3128 B
    __shared__ int gpos[NB];           //  3128 B
    __shared__ int cur[NB];            //  3128 B
    __shared__ int wsum[4];
    const int bid = blockIdx.x;
    const int tid = threadIdx.x;

    if (bid >= PBLK) {
        gemm_body(bid - PBLK, tid, x, W, bias, h);
        return;
    }

    const int k = bid;
    const int* dp = ei + k * EPB;
    const int* sp = ei + E + k * EPB;

    // block 0: zero the pad row h[N] (256 B) for agg's sentinel loads
    if (bid == 0 && tid < 64) ((unsigned*)(h + (size_t)N * CH))[tid] = 0u;

    // zero hist, then stage with fused histogram
    for (int j = tid; j < NB; j += 256) cnt[j] = 0;
    __syncthreads();
    for (int i = tid; i < EPB; i += 256) {
        int d = dp[i], s = sp[i];
        unsigned w = ((unsigned)(d >> 6) << 22) | ((unsigned)(d & (BSZ - 1)) << 16) | (unsigned)s;
        raw[i] = w;
        atomicAdd(&cnt[w >> 22], 1);
    }
    __syncthreads();

    // global bump-reserve: one atomic per non-empty bucket
    for (int j = tid; j < NB; j += 256) {
        int c = cnt[j];
        gpos[j] = j * CAP + (c ? atomicAdd(&gcur[j], c) : 0);
    }

    // exclusive scan of cnt[0..NB): thread t owns buckets [t*4, t*4+4),
    // per-wave shfl inclusive scan + 4-entry wave-sum combine (2 barriers total)
    {
        const int base = tid * 4;
        int s = 0;
#pragma unroll
        for (int i = 0; i < 4; i++) { int j = base + i; if (j < NB) s += cnt[j]; }
        const int lane = tid & 63;
        const int wid  = tid >> 6;
        int incl = s;
#pragma unroll
        for (int o = 1; o < 64; o <<= 1) {
            int u = __shfl_up(incl, o);
            if (lane >= o) incl += u;
        }
        if (lane == 63) wsum[wid] = incl;
        __syncthreads();
        int run = incl - s;
        for (int w = 0; w < wid; w++) run += wsum[w];
#pragma unroll
        for (int i = 0; i < 4; i++) {
            int j = base + i;
            if (j < NB) { lstart[j] = run; cur[j] = run; run += cnt[j]; }
        }
    }
    __syncthreads();

    // LDS sort: place each edge's local index at its sorted position
    for (int i = tid; i < EPB; i += 256) {
        int p = atomicAdd(&cur[raw[i] >> 22], 1);
        srt16[p] = (ushort)i;
    }
    __syncthreads();

    // sequential copy-out: consecutive i -> consecutive slab addresses per run
    for (int i = tid; i < EPB; i += 256) {
        unsigned w = raw[srt16[i]];
        int bkt = w >> 22;
        int gdst = gpos[bkt] + (i - lstart[bkt]);
        if (gdst < (bkt + 1) * CAP)          // defensive: never cross slab end
            pairs[gdst] = w;
    }
}

// per-uint4 consume: 8 channels (lo/hi bf16 pairs)
#define ACC8(v) do { \
    a0 += bf_lo((v).x); a1 += bf_hi((v).x); a2 += bf_lo((v).y); a3 += bf_hi((v).y); \
    a4 += bf_lo((v).z); a5 += bf_hi((v).z); a6 += bf_lo((v).w); a7 += bf_hi((v).w); } while (0)

// ---------------- fused local-CSR build + pull aggregation (1 bucket / block) ----------------
// 8 waves. Stage the bucket slab to LDS with fused hist, wave0 shfl-scan of
// PADDED counts (each node's segment rounded up to 32; pad slots hold sentinel
// src=N -> zero row, L1-resident), LDS sort -> CSR. Aggregation: wave owns 8
// nodes; QUARTER-wave (16 lanes) per edge, lane reads uint4 = 8 bf16 channels.
// R2 post-mortem: launch_bounds(512,2) left VGPR at 32 (scheduler still chased
// 8 waves/EU and sank loads to ~4 in flight). Fix: amdgpu_waves_per_eu(2,6)
// caps the occupancy target at what the 782-block grid supplies (3 blk/CU =
// 6 waves/EU -> ~85 VGPR budget), plus explicit A/B ping-pong (4+4 loads,
// distance-1 prefetch) so 4-8 uint4 loads stay in flight across iterations.
// Reduce across quarters via shfl_xor(16|32).
__global__ __launch_bounds__(512) __attribute__((amdgpu_waves_per_eu(2, 6)))
void agg_fused(const ushort* __restrict__ h,
               const unsigned* __restrict__ pairs,
               const int* __restrict__ gcur,
               float* __restrict__ out) {
    __shared__ unsigned raw[CAP];        // 10240 B
    __shared__ ushort   srt[SRTCAP];     //  9216 B
    __shared__ int hist[BSZ], offs[BSZ], cur[BSZ], cpad[BSZ];
    const int b = blockIdx.x, t = threadIdx.x;
    const int cnt = min(gcur[b], CAP);
    const int wave = t >> 6;
    const int lane = t & 63;
    const int quarter = lane >> 4;       // 0..3: which edge of a 4-edge group
    const int cq      = lane & 15;       // channel octet 0..15 (8 ch each)

    if (t < BSZ) hist[t] = 0;
    __syncthreads();

    const unsigned* slab = pairs + (size_t)b * CAP;
    for (int i = t; i < cnt; i += 512) {
        unsigned w = slab[i];
        raw[i] = w;
        atomicAdd(&hist[(w >> 16) & (BSZ - 1)], 1);
    }
    __syncthreads();

    // wave0: pad counts to multiple of 32, shfl inclusive scan (no ladder)
    if (t < BSZ) {
        int c  = hist[t];
        int cp = (c + 31) & ~31;
        int incl = cp;
#pragma unroll
        for (int o = 1; o < 64; o <<= 1) {
            int u = __shfl_up(incl, o);
            if (lane >= o) incl += u;
        }
        offs[t] = incl - cp;
        cur[t]  = incl - cp;
        cpad[t] = cp;
    }
    __syncthreads();

    // sentinel-fill the padded CSR (+32 slots of slack so the ping-pong
    // prologue of a degree-0 tail node reads sentinels, not garbage),
    // then sort actual edges into place
    const int tot = offs[BSZ - 1] + cpad[BSZ - 1];
    const int fill = min(tot + 32, SRTCAP);
    for (int i = t; i < fill; i += 512) srt[i] = (ushort)N;
    __syncthreads();
    for (int i = t; i < cnt; i += 512) {
        unsigned w = raw[i];
        int p = atomicAdd(&cur[(w >> 16) & (BSZ - 1)], 1);
        srt[p] = (ushort)(w & 0xffffu);
    }
    __syncthreads();

    const ushort* hp = h + (size_t)cq * 8;   // this lane's 8 channels

#pragma unroll 1
    for (int j = 0; j < 8; j++) {
        const int nl = wave * 8 + j;
        const int st = offs[nl];
        const int cp = cpad[nl];
        float a0 = 0.f, a1 = 0.f, a2 = 0.f, a3 = 0.f;
        float a4 = 0.f, a5 = 0.f, a6 = 0.f, a7 = 0.f;
        int base = st + quarter;
        // prologue: issue first half-group (edges 0..15 of group 0)
        int sA0 = srt[base], sA1 = srt[base + 4], sA2 = srt[base + 8], sA3 = srt[base + 12];
        uint4 vA0 = *(const uint4*)(hp + (size_t)sA0 * CH);
        uint4 vA1 = *(const uint4*)(hp + (size_t)sA1 * CH);
        uint4 vA2 = *(const uint4*)(hp + (size_t)sA2 * CH);
        uint4 vA3 = *(const uint4*)(hp + (size_t)sA3 * CH);
#pragma unroll 1
        for (int i = 0; i < cp; i += 32) {
            // issue second half-group (edges 16..31) before consuming A
            int sB0 = srt[base + 16], sB1 = srt[base + 20], sB2 = srt[base + 24], sB3 = srt[base + 28];
            uint4 vB0 = *(const uint4*)(hp + (size_t)sB0 * CH);
            uint4 vB1 = *(const uint4*)(hp + (size_t)sB1 * CH);
            uint4 vB2 = *(const uint4*)(hp + (size_t)sB2 * CH);
            uint4 vB3 = *(const uint4*)(hp + (size_t)sB3 * CH);
            ACC8(vA0); ACC8(vA1); ACC8(vA2); ACC8(vA3);
            // distance-1 prefetch of next group's first half (re-reads the
            // current base on the last iteration: uniform, L1-hot, discarded)
            const int nb = base + ((i + 32 < cp) ? 32 : 0);
            sA0 = srt[nb]; sA1 = srt[nb + 4]; sA2 = srt[nb + 8]; sA3 = srt[nb + 12];
            vA0 = *(const uint4*)(hp + (size_t)sA0 * CH);
            vA1 = *(const uint4*)(hp + (size_t)sA1 * CH);
            vA2 = *(const uint4*)(hp + (size_t)sA2 * CH);
            vA3 = *(const uint4*)(hp + (size_t)sA3 * CH);
            ACC8(vB0); ACC8(vB1); ACC8(vB2); ACC8(vB3);
            base += 32;
        }
        a0 += __shfl_xor(a0, 16); a0 += __shfl_xor(a0, 32);
        a1 += __shfl_xor(a1, 16); a1 += __shfl_xor(a1, 32);
        a2 += __shfl_xor(a2, 16); a2 += __shfl_xor(a2, 32);
        a3 += __shfl_xor(a3, 16); a3 += __shfl_xor(a3, 32);
        a4 += __shfl_xor(a4, 16); a4 += __shfl_xor(a4, 32);
        a5 += __shfl_xor(a5, 16); a5 += __shfl_xor(a5, 32);
        a6 += __shfl_xor(a6, 16); a6 += __shfl_xor(a6, 32);
        a7 += __shfl_xor(a7, 16); a7 += __shfl_xor(a7, 32);
        const int n = b * BSZ + nl;
        if (quarter == 0 && n < N) {
            float* op = out + (size_t)n * CH + cq * 8;
            *(float4*)(op)     = make_float4(a0, a1, a2, a3);
            *(float4*)(op + 4) = make_float4(a4, a5, a6, a7);
        }
    }
}

// ---------------- fallback path ----------------
__global__ __launch_bounds__(256) void gemm_only(const float* __restrict__ x,
                                                 const float* __restrict__ W,
                                                 const float* __restrict__ bias,
                                                 ushort* __restrict__ h) {
    gemm_body(blockIdx.x, threadIdx.x, x, W, bias, h);
}

__global__ void atomic_agg(const ushort* __restrict__ h, const int* __restrict__ ei,
                           float* __restrict__ out) {
    int tid = blockIdx.x * blockDim.x + threadIdx.x;
    int e  = tid >> 5;
    int cg = (tid & 31) * 4;
    if (e < E) {
        int d = ei[e];
        int s = ei[E + e];
        ushort4 v = *(const ushort4*)(h + (size_t)s * CH + cg);
        float* o = out + (size_t)d * CH + cg;
        atomicAdd(o + 0, __uint_as_float((unsigned)v.x << 16));
        atomicAdd(o + 1, __uint_as_float((unsigned)v.y << 16));
        atomicAdd(o + 2, __uint_as_float((unsigned)v.z << 16));
        atomicAdd(o + 3, __uint_as_float((unsigned)v.w << 16));
    }
}

extern "C" void kernel_launch(void* const* d_in, const int* in_sizes, int n_in,
                              void* d_out, int out_size, void* d_ws, size_t ws_size,
                              hipStream_t stream) {
    const float* x  = (const float*)d_in[0];
    const int*   ei = (const int*)d_in[1];   // [2][E] int32: row0=dst, row1=src
    const float* W  = (const float*)d_in[2];
    const float* b  = (const float*)d_in[3];
    float* out = (float*)d_out;

    char* ws = (char*)d_ws;
    ushort* h = (ushort*)(ws + H_OFF);

    if (ws_size >= REQUIRED) {
        unsigned* pairs = (unsigned*)(ws + PAIRS_OFF);
        int*      gcur  = (int*)(ws + GCUR_OFF);

        hipMemsetAsync(gcur, 0, NB * sizeof(int), stream);   // ws re-poisoned each call
        gemm_and_scatter<<<PBLK + GEMM_BLOCKS, 256, 0, stream>>>(x, W, b, h, ei, gcur, pairs);
        agg_fused<<<NB, 512, 0, stream>>>(h, pairs, gcur, out);
    } else if (ws_size >= FB_REQUIRED) {
        gemm_only<<<GEMM_BLOCKS, 256, 0, stream>>>(x, W, b, h);
        hipMemsetAsync(out, 0, (size_t)out_size * sizeof(float), stream);
        int total = E * 32;
        atomic_agg<<<(total + 255) / 256, 256, 0, stream>>>(h, ei, out);
    }
}

// Round 4
// 174.146 us; speedup vs baseline: 1.0256x; 1.0079x over previous
//
#include <hip/hip_runtime.h>

// Problem constants
constexpr int N  = 50000;    // nodes
constexpr int E  = 1600000;  // edges
constexpr int CH = 128;      // channels

// Bucket slab parameters (R4: BSZ 64->32 to double agg TLP; NB*CAP constant)
constexpr int BSZ  = 32;                   // nodes per bucket
constexpr int NB   = (N + BSZ - 1) / BSZ;  // 1563 buckets (11 bits)
constexpr int CAP  = 1280;                 // slab capacity (mean 1024, +8 sigma)
constexpr int SRTCAP = CAP + BSZ * 31 + 64; // 2336: padded CSR worst case
constexpr int PBLK = 320;                  // scatter partition blocks
constexpr int EPB  = E / PBLK;             // 5000 edges per partition block (exact)
constexpr int CPT  = (NB + 255) / 256;     // 7 buckets per thread in block scan
constexpr int GEMM_BLOCKS = N / 16;        // 3125

// Workspace layout (bytes, 256-aligned)
constexpr size_t H_OFF     = 0;                        // h bf16 [(N+1)*CH], row N = zeros
constexpr size_t H_SZ      = (size_t)(N + 1) * CH * 2; // 12,800,256 (256-aligned)
constexpr size_t PAIRS_OFF = H_OFF + H_SZ;             // slabs [NB][CAP] u32 packed
constexpr size_t PAIRS_SZ  = (size_t)NB * CAP * 4;     // 8,002,560
constexpr size_t GCUR_OFF  = PAIRS_OFF + PAIRS_SZ;     // bump cursors [NB] i32
constexpr size_t GCUR_SZ   = 6400;
constexpr size_t REQUIRED  = GCUR_OFF + GCUR_SZ;       // ~20.8 MB (<= old layout)
constexpr size_t FB_REQUIRED = H_SZ;                   // fallback: h only

// float -> bf16 round-to-nearest-even (finite inputs)
static __device__ __forceinline__ ushort f2bf(float f) {
    unsigned u = __float_as_uint(f);
    return (ushort)((u + 0x7fffu + ((u >> 16) & 1u)) >> 16);
}
static __device__ __forceinline__ float bf_lo(unsigned u) { return __uint_as_float(u << 16); }
static __device__ __forceinline__ float bf_hi(unsigned u) { return __uint_as_float(u & 0xffff0000u); }

typedef __attribute__((ext_vector_type(8))) short bf16x8;
typedef __attribute__((ext_vector_type(4))) float f32x4;

// ---------------- GEMM body: 16 rows x 128 cols per 256-thread block ----------------
// mfma_f32_16x16x32_bf16, verified layouts (m89/m91): A[m=lane&15][k=q*8+j],
// B[n=lane&15][k=q*8+j], D col=lane&15,row=q*4+reg. W converted in-register.
static __device__ __forceinline__ void gemm_body(int gb, int tid,
                                                 const float* __restrict__ x,
                                                 const float* __restrict__ W,
                                                 const float* __restrict__ bias,
                                                 ushort* __restrict__ h) {
    const int m    = tid & 15;
    const int q    = (tid >> 4) & 3;
    const int wave = tid >> 6;
    const int r0   = gb * 16;
    const int c0   = wave * 32;

    const float* xrow = x + (size_t)(r0 + m) * CH + q * 8;
    const float* wr0  = W + (size_t)(c0 + m) * CH + q * 8;
    const float* wr1  = wr0 + 16 * CH;

    f32x4 acc0 = {0.f, 0.f, 0.f, 0.f};
    f32x4 acc1 = {0.f, 0.f, 0.f, 0.f};

#pragma unroll
    for (int kc = 0; kc < CH; kc += 32) {
        float4 xa = *(const float4*)(xrow + kc);
        float4 xb = *(const float4*)(xrow + kc + 4);
        float4 wa0 = *(const float4*)(wr0 + kc);
        float4 wb0 = *(const float4*)(wr0 + kc + 4);
        float4 wa1 = *(const float4*)(wr1 + kc);
        float4 wb1 = *(const float4*)(wr1 + kc + 4);
        bf16x8 a, b0, b1;
        a[0] = (short)f2bf(xa.x); a[1] = (short)f2bf(xa.y);
        a[2] = (short)f2bf(xa.z); a[3] = (short)f2bf(xa.w);
        a[4] = (short)f2bf(xb.x); a[5] = (short)f2bf(xb.y);
        a[6] = (short)f2bf(xb.z); a[7] = (short)f2bf(xb.w);
        b0[0] = (short)f2bf(wa0.x); b0[1] = (short)f2bf(wa0.y);
        b0[2] = (short)f2bf(wa0.z); b0[3] = (short)f2bf(wa0.w);
        b0[4] = (short)f2bf(wb0.x); b0[5] = (short)f2bf(wb0.y);
        b0[6] = (short)f2bf(wb0.z); b0[7] = (short)f2bf(wb0.w);
        b1[0] = (short)f2bf(wa1.x); b1[1] = (short)f2bf(wa1.y);
        b1[2] = (short)f2bf(wa1.z); b1[3] = (short)f2bf(wa1.w);
        b1[4] = (short)f2bf(wb1.x); b1[5] = (short)f2bf(wb1.y);
        b1[6] = (short)f2bf(wb1.z); b1[7] = (short)f2bf(wb1.w);
        acc0 = __builtin_amdgcn_mfma_f32_16x16x32_bf16(a, b0, acc0, 0, 0, 0);
        acc1 = __builtin_amdgcn_mfma_f32_16x16x32_bf16(a, b1, acc1, 0, 0, 0);
    }

    const int col0 = c0 + m;
    const float bb0 = bias[col0];
    const float bb1 = bias[col0 + 16];
#pragma unroll
    for (int r = 0; r < 4; r++) {
        size_t row = (size_t)(r0 + q * 4 + r) * CH;
        h[row + col0]      = f2bf(acc0[r] + bb0);
        h[row + col0 + 16] = f2bf(acc1[r] + bb1);
    }
}

// ---------------- fused: sorted edge scatter (blocks 0..PBLK) | GEMM (rest) ----------------
// Full in-LDS counting sort so global slab writes are SEQUENTIAL per
// (bucket,block) run. Pack: bkt[11] | dstLoc[5] | src[16]. Flow: stage to LDS
// with fused int hist -> ONE global atomicAdd per bucket (bump reserve, into
// delta[]) -> per-wave shfl scan (CPT=7 buckets/thread) converting delta to
// (gpos - lstart) -> LDS sort of 16-bit local indices -> sequential copy-out
// to pairs[delta[bkt] + i]. gcur must be pre-zeroed. Block 0 zeros h row N.
__global__ __launch_bounds__(256) void gemm_and_scatter(const float* __restrict__ x,
                                                        const float* __restrict__ W,
                                                        const float* __restrict__ bias,
                                                        ushort* __restrict__ h,
                                                        const int* __restrict__ ei,
                                                        int* __restrict__ gcur,
                                                        unsigned* __restrict__ pairs) {
    __shared__ unsigned raw[EPB];      // 20000 B packed edges
    __shared__ ushort   srt16[EPB];    // 10000 B sorted local indices
    __shared__ int cnt[NB];            //  6252 B
    __shared__ int delta[NB];          //  6252 B (gpos - lstart)
    __shared__ int cur[NB];            //  6252 B (total ~48.8 KB -> 3 blocks/CU)
    __shared__ int wsum[4];
    const int bid = blockIdx.x;
    const int tid = threadIdx.x;

    if (bid >= PBLK) {
        gemm_body(bid - PBLK, tid, x, W, bias, h);
        return;
    }

    const int k = bid;
    const int* dp = ei + k * EPB;
    const int* sp = ei + E + k * EPB;

    // block 0: zero the pad row h[N] (256 B) for agg's sentinel loads
    if (bid == 0 && tid < 64) ((unsigned*)(h + (size_t)N * CH))[tid] = 0u;

    // zero hist, then stage with fused histogram
    for (int j = tid; j < NB; j += 256) cnt[j] = 0;
    __syncthreads();
    for (int i = tid; i < EPB; i += 256) {
        int d = dp[i], s = sp[i];
        unsigned w = ((unsigned)(d >> 5) << 21) | ((unsigned)(d & (BSZ - 1)) << 16) | (unsigned)s;
        raw[i] = w;
        atomicAdd(&cnt[w >> 21], 1);
    }
    __syncthreads();

    // global bump-reserve: one atomic per non-empty bucket; stash gpos in delta
    for (int j = tid; j < NB; j += 256) {
        int c = cnt[j];
        delta[j] = j * CAP + (c ? atomicAdd(&gcur[j], c) : 0);
    }
    __syncthreads();

    // exclusive scan of cnt[0..NB): thread t owns buckets [t*CPT, t*CPT+CPT),
    // per-wave shfl inclusive scan + 4-entry wave-sum combine
    {
        const int base = tid * CPT;
        int s = 0;
#pragma unroll
        for (int i = 0; i < CPT; i++) { int j = base + i; if (j < NB) s += cnt[j]; }
        const int lane = tid & 63;
        const int wid  = tid >> 6;
        int incl = s;
#pragma unroll
        for (int o = 1; o < 64; o <<= 1) {
            int u = __shfl_up(incl, o);
            if (lane >= o) incl += u;
        }
        if (lane == 63) wsum[wid] = incl;
        __syncthreads();
        int run = incl - s;
        for (int w = 0; w < wid; w++) run += wsum[w];
#pragma unroll
        for (int i = 0; i < CPT; i++) {
            int j = base + i;
            if (j < NB) { delta[j] -= run; cur[j] = run; run += cnt[j]; }
        }
    }
    __syncthreads();

    // LDS sort: place each edge's local index at its sorted position
    for (int i = tid; i < EPB; i += 256) {
        int p = atomicAdd(&cur[raw[i] >> 21], 1);
        srt16[p] = (ushort)i;
    }
    __syncthreads();

    // sequential copy-out: consecutive i -> consecutive slab addresses per run
    for (int i = tid; i < EPB; i += 256) {
        unsigned w = raw[srt16[i]];
        int bkt = w >> 21;
        int gdst = delta[bkt] + i;           // = gpos + (i - lstart)
        if (gdst < (bkt + 1) * CAP)          // defensive: never cross slab end
            pairs[gdst] = w;
    }
}

// per-uint4 consume: 8 channels (lo/hi bf16 pairs)
#define ACC8(v) do { \
    a0 += bf_lo((v).x); a1 += bf_hi((v).x); a2 += bf_lo((v).y); a3 += bf_hi((v).y); \
    a4 += bf_lo((v).z); a5 += bf_hi((v).z); a6 += bf_lo((v).w); a7 += bf_hi((v).w); } while (0)

// ---------------- fused local-CSR build + pull aggregation (1 bucket / block) ----------------
// R4: BSZ=32 -> 1563 blocks (6/CU supplied, wave-capped at 4 resident = 100%
// occupancy possible vs 40% measured at R3). LDS ~10 KB/block. 8 waves, each
// owns 4 nodes. Stage slab to LDS with fused hist, lane<32 shfl scan of PADDED
// counts (segments rounded to 32; pad slots hold sentinel src=N -> zero row,
// L1-resident), LDS sort -> CSR. QUARTER-wave (16 lanes) per edge, lane reads
// uint4 = 8 bf16 channels; A/B ping-pong with distance-1 prefetch. Reduce
// across quarters via shfl_xor(16|32).
__global__ __launch_bounds__(512)
void agg_fused(const ushort* __restrict__ h,
               const unsigned* __restrict__ pairs,
               const int* __restrict__ gcur,
               float* __restrict__ out) {
    __shared__ unsigned raw[CAP];        // 5120 B
    __shared__ ushort   srt[SRTCAP];     // 4672 B
    __shared__ int hist[BSZ], offs[BSZ], cur[BSZ], cpad[BSZ];
    const int b = blockIdx.x, t = threadIdx.x;
    const int cnt = min(gcur[b], CAP);
    const int wave = t >> 6;
    const int lane = t & 63;
    const int quarter = lane >> 4;       // 0..3: which edge of a 4-edge group
    const int cq      = lane & 15;       // channel octet 0..15 (8 ch each)

    if (t < BSZ) hist[t] = 0;
    __syncthreads();

    const unsigned* slab = pairs + (size_t)b * CAP;
    for (int i = t; i < cnt; i += 512) {
        unsigned w = slab[i];
        raw[i] = w;
        atomicAdd(&hist[(w >> 16) & (BSZ - 1)], 1);
    }
    __syncthreads();

    // lanes 0..31 of wave0: pad counts to multiple of 32, shfl inclusive scan
    if (t < BSZ) {
        int c  = hist[t];
        int cp = (c + 31) & ~31;
        int incl = cp;
#pragma unroll
        for (int o = 1; o < BSZ; o <<= 1) {
            int u = __shfl_up(incl, o);
            if (lane >= o) incl += u;
        }
        offs[t] = incl - cp;
        cur[t]  = incl - cp;
        cpad[t] = cp;
    }
    __syncthreads();

    // sentinel-fill the padded CSR (+32 slots of slack so the ping-pong
    // prologue of a degree-0 tail node reads sentinels, not garbage),
    // then sort actual edges into place
    const int tot = offs[BSZ - 1] + cpad[BSZ - 1];
    const int fill = min(tot + 32, SRTCAP);
    for (int i = t; i < fill; i += 512) srt[i] = (ushort)N;
    __syncthreads();
    for (int i = t; i < cnt; i += 512) {
        unsigned w = raw[i];
        int p = atomicAdd(&cur[(w >> 16) & (BSZ - 1)], 1);
        srt[p] = (ushort)(w & 0xffffu);
    }
    __syncthreads();

    const ushort* hp = h + (size_t)cq * 8;   // this lane's 8 channels

#pragma unroll 1
    for (int j = 0; j < 4; j++) {
        const int nl = wave * 4 + j;
        const int st = offs[nl];
        const int cp = cpad[nl];
        float a0 = 0.f, a1 = 0.f, a2 = 0.f, a3 = 0.f;
        float a4 = 0.f, a5 = 0.f, a6 = 0.f, a7 = 0.f;
        int base = st + quarter;
        // prologue: issue first half-group (edges 0..15 of group 0)
        int sA0 = srt[base], sA1 = srt[base + 4], sA2 = srt[base + 8], sA3 = srt[base + 12];
        uint4 vA0 = *(const uint4*)(hp + (size_t)sA0 * CH);
        uint4 vA1 = *(const uint4*)(hp + (size_t)sA1 * CH);
        uint4 vA2 = *(const uint4*)(hp + (size_t)sA2 * CH);
        uint4 vA3 = *(const uint4*)(hp + (size_t)sA3 * CH);
#pragma unroll 1
        for (int i = 0; i < cp; i += 32) {
            // issue second half-group (edges 16..31) before consuming A
            int sB0 = srt[base + 16], sB1 = srt[base + 20], sB2 = srt[base + 24], sB3 = srt[base + 28];
            uint4 vB0 = *(const uint4*)(hp + (size_t)sB0 * CH);
            uint4 vB1 = *(const uint4*)(hp + (size_t)sB1 * CH);
            uint4 vB2 = *(const uint4*)(hp + (size_t)sB2 * CH);
            uint4 vB3 = *(const uint4*)(hp + (size_t)sB3 * CH);
            ACC8(vA0); ACC8(vA1); ACC8(vA2); ACC8(vA3);
            // distance-1 prefetch of next group's first half (re-reads the
            // current base on the last iteration: uniform, L1-hot, discarded)
            const int nb = base + ((i + 32 < cp) ? 32 : 0);
            sA0 = srt[nb]; sA1 = srt[nb + 4]; sA2 = srt[nb + 8]; sA3 = srt[nb + 12];
            vA0 = *(const uint4*)(hp + (size_t)sA0 * CH);
            vA1 = *(const uint4*)(hp + (size_t)sA1 * CH);
            vA2 = *(const uint4*)(hp + (size_t)sA2 * CH);
            vA3 = *(const uint4*)(hp + (size_t)sA3 * CH);
            ACC8(vB0); ACC8(vB1); ACC8(vB2); ACC8(vB3);
            base += 32;
        }
        a0 += __shfl_xor(a0, 16); a0 += __shfl_xor(a0, 32);
        a1 += __shfl_xor(a1, 16); a1 += __shfl_xor(a1, 32);
        a2 += __shfl_xor(a2, 16); a2 += __shfl_xor(a2, 32);
        a3 += __shfl_xor(a3, 16); a3 += __shfl_xor(a3, 32);
        a4 += __shfl_xor(a4, 16); a4 += __shfl_xor(a4, 32);
        a5 += __shfl_xor(a5, 16); a5 += __shfl_xor(a5, 32);
        a6 += __shfl_xor(a6, 16); a6 += __shfl_xor(a6, 32);
        a7 += __shfl_xor(a7, 16); a7 += __shfl_xor(a7, 32);
        const int n = b * BSZ + nl;
        if (quarter == 0 && n < N) {
            float* op = out + (size_t)n * CH + cq * 8;
            *(float4*)(op)     = make_float4(a0, a1, a2, a3);
            *(float4*)(op + 4) = make_float4(a4, a5, a6, a7);
        }
    }
}

// ---------------- fallback path ----------------
__global__ __launch_bounds__(256) void gemm_only(const float* __restrict__ x,
                                                 const float* __restrict__ W,
                                                 const float* __restrict__ bias,
                                                 ushort* __restrict__ h) {
    gemm_body(blockIdx.x, threadIdx.x, x, W, bias, h);
}

__global__ void atomic_agg(const ushort* __restrict__ h, const int* __restrict__ ei,
                           float* __restrict__ out) {
    int tid = blockIdx.x * blockDim.x + threadIdx.x;
    int e  = tid >> 5;
    int cg = (tid & 31) * 4;
    if (e < E) {
        int d = ei[e];
        int s = ei[E + e];
        ushort4 v = *(const ushort4*)(h + (size_t)s * CH + cg);
        float* o = out + (size_t)d * CH + cg;
        atomicAdd(o + 0, __uint_as_float((unsigned)v.x << 16));
        atomicAdd(o + 1, __uint_as_float((unsigned)v.y << 16));
        atomicAdd(o + 2, __uint_as_float((unsigned)v.z << 16));
        atomicAdd(o + 3, __uint_as_float((unsigned)v.w << 16));
    }
}

extern "C" void kernel_launch(void* const* d_in, const int* in_sizes, int n_in,
                              void* d_out, int out_size, void* d_ws, size_t ws_size,
                              hipStream_t stream) {
    const float* x  = (const float*)d_in[0];
    const int*   ei = (const int*)d_in[1];   // [2][E] int32: row0=dst, row1=src
    const float* W  = (const float*)d_in[2];
    const float* b  = (const float*)d_in[3];
    float* out = (float*)d_out;

    char* ws = (char*)d_ws;
    ushort* h = (ushort*)(ws + H_OFF);

    if (ws_size >= REQUIRED) {
        unsigned* pairs = (unsigned*)(ws + PAIRS_OFF);
        int*      gcur  = (int*)(ws + GCUR_OFF);

        hipMemsetAsync(gcur, 0, NB * sizeof(int), stream);   // ws re-poisoned each call
        gemm_and_scatter<<<PBLK + GEMM_BLOCKS, 256, 0, stream>>>(x, W, b, h, ei, gcur, pairs);
        agg_fused<<<NB, 512, 0, stream>>>(h, pairs, gcur, out);
    } else if (ws_size >= FB_REQUIRED) {
        gemm_only<<<GEMM_BLOCKS, 256, 0, stream>>>(x, W, b, h);
        hipMemsetAsync(out, 0, (size_t)out_size * sizeof(float), stream);
        int total = E * 32;
        atomic_agg<<<(total + 255) / 256, 256, 0, stream>>>(h, ei, out);
    }
}